// Round 8
// baseline (615.508 us; speedup 1.0000x reference)
//
#include <hip/hip_runtime.h>
#include <math.h>

#define H_DIM 2880
#define E_NUM 32
#define TOPK 4
#define TT 16        // tokens per block -> grid 1024 = 4 blocks/CU
#define KW 64        // k-window per stage (pure-b128: lane quad at ks*4)
#define NSTG 45      // H_DIM / KW
#define LGR 36       // logit row stride: 16B-aligned, %32=4 (bank stagger)

// R10: no-LDS register-streaming gate. R8/R9/orig tied at ~275us across three
// different sync structures -> kernel (~54us = dur - 2x110us poison fills) is
// bound by a structure-invariant resource. Model: the per-CU LDS pipe
// (24 ds_read/wave/stage ~ 29-43us serial) -- pure overhead since w is
// L1/L2-hot and x slices are lane-exclusive. This kernel has ZERO LDS / ZERO
// barriers in the main loop:
//  lane = (ks=lane>>2, tt=lane&3); wave wq -> experts wq*8..+7.
//  acc[4tok][8exp]; k covered as {s*64 + ks*4 + u}, folded by shfl at end.
//  x: 4 reg-quads/stage, lane-exclusive, wave-dense (1KB/instr, 256B-aligned
//     window; 4 waves share via L1; HBM reads x exactly once = 188.7 MB).
//  w: 8 reg-quads/stage via uniform SGPR row base + shared voffset (L1-hot,
//     12KB window/CU); single-buffer rolling reload right after last use.
//  x double-buffered xA/xB with manual 2x unroll (static indices only).
// ~115 VGPR -> 4 waves/SIMD. Floors: HBM 30us, VALU 19us -> predict ~32us.
__global__ __launch_bounds__(256, 4) void gate_fused(
    const float* __restrict__ x, const float* __restrict__ w,
    const float* __restrict__ bias, float* __restrict__ out, int T) {
    __shared__ float lg[TT * LGR];
    const int tid = threadIdx.x;
    const int lane = tid & 63;
    const int wq = __builtin_amdgcn_readfirstlane(tid >> 6);
    const int tt = lane & 3;       // token quad: tokens tt*4..+3
    const int ks = lane >> 2;      // k-slice: dw ks*4..+3 within each KW window
    const int t0 = blockIdx.x * TT;
    const int ks4 = ks * 4;

    // per-lane x row pointers (VGPR pairs, advanced by KW each stage)
    const float* xr[4];
#pragma unroll
    for (int i = 0; i < 4; ++i)
        xr[i] = x + (size_t)(t0 + tt * 4 + i) * H_DIM + ks4;
    // wave-uniform w row bases (SGPR pairs; loads use shared per-lane voffset)
    const float* wrow[8];
#pragma unroll
    for (int j = 0; j < 8; ++j)
        wrow[j] = w + (size_t)(wq * 8 + j) * H_DIM;

    float acc[4][8];
#pragma unroll
    for (int i = 0; i < 4; ++i)
#pragma unroll
        for (int j = 0; j < 8; ++j) acc[i][j] = 0.f;

    float4 xA[4], xB[4], wc[8];
    int soff = ks4;
    // preload stage 0; advance xr to stage 1
#pragma unroll
    for (int i = 0; i < 4; ++i) { xA[i] = *(const float4*)xr[i]; xr[i] += KW; }
#pragma unroll
    for (int j = 0; j < 8; ++j) wc[j] = *(const float4*)(wrow[j] + soff);

    // STAGE_R: prefetch x(s+1)->XN; compute s with XC,wc; reload wc<-w(s+1).
    // wc[j] reload sits right after its last FMA use: ~7/8-stage flight (~220
    // cyc) covers L1/L2 latency; WAR on the reg is safe (in-order issue).
#define STAGE_R(XC, XN)                                                     \
    do {                                                                    \
        _Pragma("unroll")                                                   \
        for (int i = 0; i < 4; ++i) {                                       \
            XN[i] = *(const float4*)xr[i];                                  \
            xr[i] += KW;                                                    \
        }                                                                   \
        soff += KW;                                                         \
        _Pragma("unroll")                                                   \
        for (int j = 0; j < 8; ++j) {                                       \
            _Pragma("unroll")                                               \
            for (int i = 0; i < 4; ++i)                                     \
                acc[i][j] += XC[i].x * wc[j].x + XC[i].y * wc[j].y +        \
                             XC[i].z * wc[j].z + XC[i].w * wc[j].w;         \
            wc[j] = *(const float4*)(wrow[j] + soff);                       \
        }                                                                   \
    } while (0)

    // 22 double-iters cover s = 0..43; xA then holds s=44, wc holds w(44).
    for (int it = 0; it < (NSTG - 1) / 2; ++it) {
        STAGE_R(xA, xB);
        STAGE_R(xB, xA);
    }
    // final stage s = 44 (no prefetch, no reload)
#pragma unroll
    for (int j = 0; j < 8; ++j)
#pragma unroll
        for (int i = 0; i < 4; ++i)
            acc[i][j] += xA[i].x * wc[j].x + xA[i].y * wc[j].y +
                         xA[i].z * wc[j].z + xA[i].w * wc[j].w;

    // fold k across ks (lane bits 2..5): partners share tt and wave
#pragma unroll
    for (int i = 0; i < 4; ++i)
#pragma unroll
        for (int j = 0; j < 8; ++j) {
            float v = acc[i][j];
            v += __shfl_xor(v, 4, 64);
            v += __shfl_xor(v, 8, 64);
            v += __shfl_xor(v, 16, 64);
            v += __shfl_xor(v, 32, 64);
            acc[i][j] = v;
        }

    // lanes 0..3 (ks==0, tt=lane) publish logits + bias
    if (ks == 0) {
#pragma unroll
        for (int i = 0; i < 4; ++i)
#pragma unroll
            for (int j = 0; j < 8; ++j)
                lg[(tt * 4 + i) * LGR + wq * 8 + j] =
                    acc[i][j] + bias[wq * 8 + j];
    }
    __syncthreads();

    // first 16 lanes: per-token top-4 + softmax + store
    if (tid < TT) {
        const int t = t0 + tid;
        float logit[E_NUM];
#pragma unroll
        for (int j2 = 0; j2 < 8; ++j2) {
            float4 v = *(const float4*)&lg[tid * LGR + j2 * 4];
            logit[j2 * 4] = v.x; logit[j2 * 4 + 1] = v.y;
            logit[j2 * 4 + 2] = v.z; logit[j2 * 4 + 3] = v.w;
        }

        // top-4 descending, ties -> lowest index (strict >, ascending scan)
        int idx[TOPK];
        float val[TOPK];
#pragma unroll
        for (int k = 0; k < TOPK; ++k) {
            float best = -INFINITY;
            int bi = 0;
#pragma unroll
            for (int e = 0; e < E_NUM; ++e) {
                bool taken = false;
                for (int p2 = 0; p2 < k; ++p2) taken = taken || (idx[p2] == e);
                float v = logit[e];
                if (!taken && v > best) { best = v; bi = e; }
            }
            idx[k] = bi;
            val[k] = best;
        }
        float ex[TOPK], ssum = 0.f;
#pragma unroll
        for (int k = 0; k < TOPK; ++k) { ex[k] = expf(val[k] - val[0]); ssum += ex[k]; }
        const float inv = 1.f / ssum;

        *(float4*)(out + (size_t)t * 4) =
            make_float4((float)idx[0], (float)idx[1], (float)idx[2], (float)idx[3]);
        *(float4*)(out + (size_t)T * 4 + (size_t)t * 4) =
            make_float4(ex[0] * inv, ex[1] * inv, ex[2] * inv, ex[3] * inv);
    }
}

extern "C" void kernel_launch(void* const* d_in, const int* in_sizes, int n_in,
                              void* d_out, int out_size, void* d_ws, size_t ws_size,
                              hipStream_t stream) {
    const float* x    = (const float*)d_in[0];  // [B,S,H] fp32
    const float* w    = (const float*)d_in[1];  // [E,H] fp32
    const float* bias = (const float*)d_in[2];  // [E] fp32
    float* out = (float*)d_out;

    const int T = in_sizes[0] / H_DIM;  // 16384

    gate_fused<<<dim3(T / TT), 256, 0, stream>>>(x, w, bias, out, T);
}